// Round 3
// baseline (154.520 us; speedup 1.0000x reference)
//
#include <hip/hip_runtime.h>

#define NUM_FRAME 300
#define LEN_FRAME 512
#define T_LEN     20000

typedef float floatx4 __attribute__((ext_vector_type(4)));
typedef int   intx8   __attribute__((ext_vector_type(8)));
typedef int   int2a   __attribute__((ext_vector_type(2), aligned(4)));
typedef int   int2w   __attribute__((ext_vector_type(2)));   // natural 8B align -> ds_write_b64
typedef unsigned int uint32;

// Per-pair LDS layout (BYTES), fp8 e4m3 samples (scaled x32). ext a8[x]=a[x&511].
//  A0 [0,624):    ext x in [400,1024) at byte x-400.  il<8 lanes read here:
//    base dword 28+8q-4il EVEN.
//  A1 [628,1260): ext x in [272,904)  at byte 628+(x-272). A1_OFF=628 == 4 mod 8:
//    il>=8 lanes read ODD dwords -> combined wave covers all 32 banks,
//    <=2 distinct addr/bank per read2 half (R0/R1-verified parity scheme; R2's
//    16B-aligned ds_read_b128 pattern measured +8 conflict cyc/instr -> reverted).
//  B [1264,3376): 4 shift-copies b_s[p]=a8[(p+s)&511], p in [0,528), stride 528
//    (132 dw == 4 mod 32): bank = 28+4s+t+8q+c -> exactly 2 lanes/bank, distinct
//    addrs = free (enumerated; same class as R1's verified 544 scheme).
#define A1_OFF  628
#define B_OFF   1264
#define B_STR   528
#define PAIR8   3376          // 16-aligned; 8 pairs = 27008 B -> 6 blocks/CU

// Compile-time Hann*32 window table: w[n] = 32 * sin^2(pi*n/512) (Taylor, ~1e-16).
struct alignas(16) WinTab {
    float w[512];
    constexpr WinTab() : w{} {
        for (int n = 0; n < 512; ++n) {
            int mm = (n <= 256) ? n : 512 - n;
            double x = 3.14159265358979323846 * (double)mm / 512.0;
            double t = x, s = x, x2 = x * x;
            for (int i = 1; i <= 10; ++i) { t *= -x2 / (double)((2 * i) * (2 * i + 1)); s += t; }
            w[n] = (float)(32.0 * s * s);
        }
    }
};
__device__ const WinTab wtab{};

__global__ __launch_bounds__(256, 6) void acorr_fp8(const float* __restrict__ in,
                                                    float* __restrict__ out) {
    __shared__ __align__(16) char lds8[8 * PAIR8];   // 27008 B

    const int tid = threadIdx.x;
    const int fj  = tid >> 6;          // frame within block (wave fj computes frame fj)
    const int m   = tid & 63;          // owns samples x0..x0+7
    const int x0  = 8 * m;

    // ---------------- staging: window (table) -> fp8(x32) -> A0/A1 + 4 B shift-images ----------------
    {
        const int G  = blockIdx.x * 4 + fj;
        const int bc = (int)((unsigned)G / (unsigned)NUM_FRAME);
        const int fr = G - bc * NUM_FRAME;
        // exact: floor(fr*19488/299); fr=299 -> exactly 19488 (matches f64 linspace).
        const int start = (int)(((unsigned)fr * (unsigned)(T_LEN - LEN_FRAME))
                                / (unsigned)(NUM_FRAME - 1));
        const float2* src = (const float2*)(in + (size_t)2 * ((size_t)bc * T_LEN + start));

        const int cn = (x0 + 8) & 511;                 // circular context base (3 bytes used)

        const float2 v0 = src[x0],     v1 = src[x0 + 1], v2 = src[x0 + 2], v3 = src[x0 + 3];
        const float2 v4 = src[x0 + 4], v5 = src[x0 + 5], v6 = src[x0 + 6], v7 = src[x0 + 7];
        const float2 c0 = src[cn],     c1 = src[cn + 1], c2 = src[cn + 2], c3 = src[cn + 3];

        const floatx4 wva = *(const floatx4*)&wtab.w[x0];
        const floatx4 wvb = *(const floatx4*)&wtab.w[x0 + 4];
        const floatx4 wvc = *(const floatx4*)&wtab.w[cn];

        #pragma unroll
        for (int c = 0; c < 2; ++c) {
            float f0 = (c ? v0.y : v0.x) * wva[0];
            float f1 = (c ? v1.y : v1.x) * wva[1];
            float f2 = (c ? v2.y : v2.x) * wva[2];
            float f3 = (c ? v3.y : v3.x) * wva[3];
            float f4 = (c ? v4.y : v4.x) * wvb[0];
            float f5 = (c ? v5.y : v5.x) * wvb[1];
            float f6 = (c ? v6.y : v6.x) * wvb[2];
            float f7 = (c ? v7.y : v7.x) * wvb[3];
            float g0 = (c ? c0.y : c0.x) * wvc[0];
            float g1 = (c ? c1.y : c1.x) * wvc[1];
            float g2 = (c ? c2.y : c2.x) * wvc[2];
            float g3 = (c ? c3.y : c3.x) * wvc[3];

            int d0 = __builtin_amdgcn_cvt_pk_fp8_f32(f0, f1, 0,  false);
            d0     = __builtin_amdgcn_cvt_pk_fp8_f32(f2, f3, d0, true);
            int d1 = __builtin_amdgcn_cvt_pk_fp8_f32(f4, f5, 0,  false);
            d1     = __builtin_amdgcn_cvt_pk_fp8_f32(f6, f7, d1, true);
            int d2 = __builtin_amdgcn_cvt_pk_fp8_f32(g0, g1, 0,  false);
            d2     = __builtin_amdgcn_cvt_pk_fp8_f32(g2, g3, d2, true);

            char* P = &lds8[(fj * 2 + c) * PAIR8];
            // A0: ext [400,1024) at byte x-400
            *(int2w*)(P + 112 + x0) = (int2w){d0, d1};            // ext [512,1024)
            if (x0 >= 400)
                *(int2w*)(P + x0 - 400) = (int2w){d0, d1};        // ext [400,512)
            // A1: ext [272,904) at byte 628+(x-272)
            if (x0 <= 384)
                *(int2w*)(P + A1_OFF + 240 + x0) = (int2w){d0, d1};   // ext [512,904)
            if (x0 >= 272)
                *(int2w*)(P + A1_OFF + x0 - 272) = (int2w){d0, d1};   // ext [272,512)
            #pragma unroll
            for (int s = 0; s < 4; ++s) {
                int e0 = (s == 0) ? d0
                       : (int)__builtin_amdgcn_alignbyte((uint32)d1, (uint32)d0, (uint32)s);
                int e1 = (s == 0) ? d1
                       : (int)__builtin_amdgcn_alignbyte((uint32)d2, (uint32)d1, (uint32)s);
                *(int2w*)(P + B_OFF + B_STR * s + x0) = (int2w){e0, e1};
                if (x0 < 16)                                       // periodic tail [512,528)
                    *(int2w*)(P + B_OFF + B_STR * s + x0 + 512) = (int2w){e0, e1};
            }
        }
    }
    __syncthreads();

    // ---------------- MFMA main: wave = frame; both channels; 4 x (16x16x128 f8f6f4 fp8) ----------------
    const int lane = tid & 63;
    const int il   = lane & 15;    // A row i / B col j
    const int q    = lane >> 4;    // k-block

    const char* P0 = &lds8[(fj * 2) * PAIR8];                     // ch0; ch1 at +PAIR8
    // A fragment base: ext 512 + 32q - 16il (+128u). il<8 -> A0 (even dwords),
    // il>=8 -> A1 (odd dwords). 4x ds_read2_b32 per fragment, conflict-free.
    const char* aP = P0 + 32 * q - 16 * il + ((il & 8) ? (A1_OFF + 240) : 112);
    const char* bP = P0 + B_OFF + B_STR * (il & 3) + 4 * (il >> 2) + 32 * q;

    floatx4 acc0 = {0.f, 0.f, 0.f, 0.f};
    floatx4 acc1 = {0.f, 0.f, 0.f, 0.f};
    #pragma unroll
    for (int u = 0; u < 4; ++u) {
        const int o = 128 * u;
        // ch0
        {
            int2a a0 = *(const int2a*)(aP + o);
            int2a a1 = *(const int2a*)(aP + o + 8);
            int2a a2 = *(const int2a*)(aP + o + 16);
            int2a a3 = *(const int2a*)(aP + o + 24);
            int2a b0 = *(const int2a*)(bP + o);
            int2a b1 = *(const int2a*)(bP + o + 8);
            int2a b2 = *(const int2a*)(bP + o + 16);
            int2a b3 = *(const int2a*)(bP + o + 24);
            intx8 a = {a0.x, a0.y, a1.x, a1.y, a2.x, a2.y, a3.x, a3.y};
            intx8 b = {b0.x, b0.y, b1.x, b1.y, b2.x, b2.y, b3.x, b3.y};
            acc0 = __builtin_amdgcn_mfma_scale_f32_16x16x128_f8f6f4(
                a, b, acc0, 0, 0, 0, 0x7F7F7F7F, 0, 0x7F7F7F7F);  // scales = 1.0 (e8m0 127)
        }
        // ch1
        {
            int2a a0 = *(const int2a*)(aP + PAIR8 + o);
            int2a a1 = *(const int2a*)(aP + PAIR8 + o + 8);
            int2a a2 = *(const int2a*)(aP + PAIR8 + o + 16);
            int2a a3 = *(const int2a*)(aP + PAIR8 + o + 24);
            int2a b0 = *(const int2a*)(bP + PAIR8 + o);
            int2a b1 = *(const int2a*)(bP + PAIR8 + o + 8);
            int2a b2 = *(const int2a*)(bP + PAIR8 + o + 16);
            int2a b3 = *(const int2a*)(bP + PAIR8 + o + 24);
            intx8 a = {a0.x, a0.y, a1.x, a1.y, a2.x, a2.y, a3.x, a3.y};
            intx8 b = {b0.x, b0.y, b1.x, b1.y, b2.x, b2.y, b3.x, b3.y};
            acc1 = __builtin_amdgcn_mfma_scale_f32_16x16x128_f8f6f4(
                a, b, acc1, 0, 0, 0, 0x7F7F7F7F, 0, 0x7F7F7F7F);
        }
    }

    // ---------------- epilogue: per-channel relu + 1/sqrt(acf0), in-register mean, store ----------------
    // C/D layout: col j = lane&15, row i = 4q + reg -> lag = 16i + j. acc = 1024*acf.
    float n00 = __int_as_float(__builtin_amdgcn_readfirstlane(__float_as_int(acc0[0])));
    float n01 = __int_as_float(__builtin_amdgcn_readfirstlane(__float_as_int(acc1[0])));
    float n0r0 = fmaxf(n00, 0.f);
    float n0r1 = fmaxf(n01, 0.f);
    float inv0 = (n0r0 == 0.f) ? (1.0f / 1024.0f) : (rsqrtf(n0r0) * (1.0f / 32.0f));
    float inv1 = (n0r1 == 0.f) ? (1.0f / 1024.0f) : (rsqrtf(n0r1) * (1.0f / 32.0f));

    const int G = blockIdx.x * 4 + fj;
    float* ob = out + (size_t)G * 256 + q * 64 + il;
    ob[ 0] = 0.5f * (fmaxf(acc0[0], 0.f) * inv0 + fmaxf(acc1[0], 0.f) * inv1);
    ob[16] = 0.5f * (fmaxf(acc0[1], 0.f) * inv0 + fmaxf(acc1[1], 0.f) * inv1);
    ob[32] = 0.5f * (fmaxf(acc0[2], 0.f) * inv0 + fmaxf(acc1[2], 0.f) * inv1);
    ob[48] = 0.5f * (fmaxf(acc0[3], 0.f) * inv0 + fmaxf(acc1[3], 0.f) * inv1);
}

extern "C" void kernel_launch(void* const* d_in, const int* in_sizes, int n_in,
                              void* d_out, int out_size, void* d_ws, size_t ws_size,
                              hipStream_t stream) {
    const float* in = (const float*)d_in[0];
    float* out = (float*)d_out;
    dim3 grid(15000);    // 60000 frames / 4 per block (1 wave per frame, both channels)
    dim3 block(256);
    acorr_fp8<<<grid, block, 0, stream>>>(in, out);
}

// Round 5
// 120.196 us; speedup vs baseline: 1.2856x; 1.2856x over previous
//
#include <hip/hip_runtime.h>

#define NUM_FRAME 300
#define LEN_FRAME 512
#define T_LEN     20000

typedef float floatx4 __attribute__((ext_vector_type(4)));
typedef int   intx8   __attribute__((ext_vector_type(8)));
typedef int   int2a   __attribute__((ext_vector_type(2), aligned(4)));
typedef int   int2w   __attribute__((ext_vector_type(2)));   // 8B-aligned -> ds_write_b64
typedef unsigned int uint32;

// Per-pair LDS layout (BYTES), fp8 e4m3 samples (scaled x32). ext a8[x]=a[x&511].
//
// k-slot bijection (applied to BOTH operands -> dot product invariant):
//   MFMA slot (q = lane>>4, t = chunk, r) holds logical k = 8q + 32t + r + 128u.
// This makes every read2_b32's lane-varying dword term (2q - 4il) spread with
// q-coefficient 2 -> all 16 same-parity banks, <=2 distinct addr/bank =
// R1's MEASURED-free pattern (R2/R3 had q-coeff 8 -> mod-4 bank collapse,
// 4-8 lanes/bank -> 512-1024 conflict cyc/block).
//
//  A0 [0,624):    ext x in [400,1024) at byte x-400. il<8 lanes: dword even.
//  A1 [628,1260): ext x in [272,904)  at byte 628+(x-272). 628 == 4 mod 8 ->
//    il>=8 lanes read ODD dwords -> wave covers all 32 banks.
//  B [1264,...):  4 shift-images b_s[p]=a8[(p+s)&511], p in [0,528), stride 536
//    (134 dw == 6 mod 32): bank = 28 + 6s + h + 2q + shift -> enumerated <=2
//    distinct addr/bank (overlaps are broadcasts or 2-distinct).
#define A1_OFF  628
#define B_OFF   1264
#define B_STR   536
#define PAIR8   3408          // 1264 + 4*536; 8 pairs = 27264 B -> 6 blocks/CU

// Compile-time Hann*32 window table: w[n] = 32 * sin^2(pi*n/512) (Taylor, ~1e-16).
struct alignas(16) WinTab {
    float w[512];
    constexpr WinTab() : w{} {
        for (int n = 0; n < 512; ++n) {
            int mm = (n <= 256) ? n : 512 - n;
            double x = 3.14159265358979323846 * (double)mm / 512.0;
            double t = x, s = x, x2 = x * x;
            for (int i = 1; i <= 10; ++i) { t *= -x2 / (double)((2 * i) * (2 * i + 1)); s += t; }
            w[n] = (float)(32.0 * s * s);
        }
    }
};
__device__ const WinTab wtab{};

__global__ __launch_bounds__(256, 6) void acorr_fp8(const float* __restrict__ in,
                                                    float* __restrict__ out) {
    __shared__ __align__(16) char lds8[8 * PAIR8];   // 27264 B

    const int tid = threadIdx.x;
    const int fj  = tid >> 6;          // frame within block (wave fj computes frame fj)
    const int m   = tid & 63;          // owns samples x0..x0+7
    const int x0  = 8 * m;

    // ---------------- staging: window (table) -> fp8(x32) -> A0/A1 + 4 B shift-images ----------------
    {
        const int G  = blockIdx.x * 4 + fj;
        const int bc = (int)((unsigned)G / (unsigned)NUM_FRAME);
        const int fr = G - bc * NUM_FRAME;
        // exact: floor(fr*19488/299); fr=299 -> exactly 19488 (matches f64 linspace).
        const int start = (int)(((unsigned)fr * (unsigned)(T_LEN - LEN_FRAME))
                                / (unsigned)(NUM_FRAME - 1));
        const float2* src = (const float2*)(in + (size_t)2 * ((size_t)bc * T_LEN + start));

        const int cn = (x0 + 8) & 511;                 // circular context base (3 bytes used)

        const float2 v0 = src[x0],     v1 = src[x0 + 1], v2 = src[x0 + 2], v3 = src[x0 + 3];
        const float2 v4 = src[x0 + 4], v5 = src[x0 + 5], v6 = src[x0 + 6], v7 = src[x0 + 7];
        const float2 c0 = src[cn],     c1 = src[cn + 1], c2 = src[cn + 2], c3 = src[cn + 3];

        const floatx4 wva = *(const floatx4*)&wtab.w[x0];
        const floatx4 wvb = *(const floatx4*)&wtab.w[x0 + 4];
        const floatx4 wvc = *(const floatx4*)&wtab.w[cn];

        #pragma unroll
        for (int c = 0; c < 2; ++c) {
            float f0 = (c ? v0.y : v0.x) * wva[0];
            float f1 = (c ? v1.y : v1.x) * wva[1];
            float f2 = (c ? v2.y : v2.x) * wva[2];
            float f3 = (c ? v3.y : v3.x) * wva[3];
            float f4 = (c ? v4.y : v4.x) * wvb[0];
            float f5 = (c ? v5.y : v5.x) * wvb[1];
            float f6 = (c ? v6.y : v6.x) * wvb[2];
            float f7 = (c ? v7.y : v7.x) * wvb[3];
            float g0 = (c ? c0.y : c0.x) * wvc[0];
            float g1 = (c ? c1.y : c1.x) * wvc[1];
            float g2 = (c ? c2.y : c2.x) * wvc[2];
            float g3 = (c ? c3.y : c3.x) * wvc[3];

            int d0 = __builtin_amdgcn_cvt_pk_fp8_f32(f0, f1, 0,  false);
            d0     = __builtin_amdgcn_cvt_pk_fp8_f32(f2, f3, d0, true);
            int d1 = __builtin_amdgcn_cvt_pk_fp8_f32(f4, f5, 0,  false);
            d1     = __builtin_amdgcn_cvt_pk_fp8_f32(f6, f7, d1, true);
            int d2 = __builtin_amdgcn_cvt_pk_fp8_f32(g0, g1, 0,  false);
            d2     = __builtin_amdgcn_cvt_pk_fp8_f32(g2, g3, d2, true);

            char* P = &lds8[(fj * 2 + c) * PAIR8];
            // A0: ext [400,1024) at byte x-400
            *(int2w*)(P + 112 + x0) = (int2w){d0, d1};            // ext [512,1024)
            if (x0 >= 400)
                *(int2w*)(P + x0 - 400) = (int2w){d0, d1};        // ext [400,512)
            // A1: ext [272,904) at byte 628+(x-272)  (addr == 4 mod 8 -> align-4 type)
            if (x0 <= 384)
                *(int2a*)(P + A1_OFF + 240 + x0) = (int2a){d0, d1};   // ext [512,904)
            if (x0 >= 272)
                *(int2a*)(P + A1_OFF + x0 - 272) = (int2a){d0, d1};   // ext [272,512)
            #pragma unroll
            for (int s = 0; s < 4; ++s) {
                int e0 = (s == 0) ? d0
                       : (int)__builtin_amdgcn_alignbyte((uint32)d1, (uint32)d0, (uint32)s);
                int e1 = (s == 0) ? d1
                       : (int)__builtin_amdgcn_alignbyte((uint32)d2, (uint32)d1, (uint32)s);
                *(int2w*)(P + B_OFF + B_STR * s + x0) = (int2w){e0, e1};
                if (x0 < 16)                                       // periodic tail [512,528)
                    *(int2w*)(P + B_OFF + B_STR * s + x0 + 512) = (int2w){e0, e1};
            }
        }
    }
    __syncthreads();

    // ---------------- MFMA main: wave = frame; both channels; 4 x (16x16x128 f8f6f4 fp8) ----------------
    const int lane = tid & 63;
    const int il   = lane & 15;    // A row i / B col j
    const int q    = lane >> 4;

    const char* P0 = &lds8[(fj * 2) * PAIR8];                     // ch0; ch1 at +PAIR8
    // slot (q,t) -> logical k = 8q + 32t (+128u).
    // A row il slot-chunk: ext 512 - 16il + 8q + 32t + 128u.
    //   il<8 -> A0 (even dwords), il>=8 -> A1 (odd dwords).
    const char* aP = P0 + 8 * q - 16 * il + ((il & 8) ? (A1_OFF + 240) : 112);
    // B col j = s + 4h: image_s[8q + 4h + 32t + 128u].
    const char* bP = P0 + B_OFF + B_STR * (il & 3) + 4 * (il >> 2) + 8 * q;

    floatx4 acc0 = {0.f, 0.f, 0.f, 0.f};
    floatx4 acc1 = {0.f, 0.f, 0.f, 0.f};
    #pragma unroll
    for (int u = 0; u < 4; ++u) {
        const int o = 128 * u;
        // ch0
        {
            int2a a0 = *(const int2a*)(aP + o);
            int2a a1 = *(const int2a*)(aP + o + 32);
            int2a a2 = *(const int2a*)(aP + o + 64);
            int2a a3 = *(const int2a*)(aP + o + 96);
            int2a b0 = *(const int2a*)(bP + o);
            int2a b1 = *(const int2a*)(bP + o + 32);
            int2a b2 = *(const int2a*)(bP + o + 64);
            int2a b3 = *(const int2a*)(bP + o + 96);
            intx8 a = {a0.x, a0.y, a1.x, a1.y, a2.x, a2.y, a3.x, a3.y};
            intx8 b = {b0.x, b0.y, b1.x, b1.y, b2.x, b2.y, b3.x, b3.y};
            acc0 = __builtin_amdgcn_mfma_scale_f32_16x16x128_f8f6f4(
                a, b, acc0, 0, 0, 0, 0x7F7F7F7F, 0, 0x7F7F7F7F);  // scales = 1.0 (e8m0 127)
        }
        // ch1
        {
            int2a a0 = *(const int2a*)(aP + PAIR8 + o);
            int2a a1 = *(const int2a*)(aP + PAIR8 + o + 32);
            int2a a2 = *(const int2a*)(aP + PAIR8 + o + 64);
            int2a a3 = *(const int2a*)(aP + PAIR8 + o + 96);
            int2a b0 = *(const int2a*)(bP + PAIR8 + o);
            int2a b1 = *(const int2a*)(bP + PAIR8 + o + 32);
            int2a b2 = *(const int2a*)(bP + PAIR8 + o + 64);
            int2a b3 = *(const int2a*)(bP + PAIR8 + o + 96);
            intx8 a = {a0.x, a0.y, a1.x, a1.y, a2.x, a2.y, a3.x, a3.y};
            intx8 b = {b0.x, b0.y, b1.x, b1.y, b2.x, b2.y, b3.x, b3.y};
            acc1 = __builtin_amdgcn_mfma_scale_f32_16x16x128_f8f6f4(
                a, b, acc1, 0, 0, 0, 0x7F7F7F7F, 0, 0x7F7F7F7F);
        }
    }

    // ---------------- epilogue: per-channel relu + 1/sqrt(acf0), in-register mean, store ----------------
    // C/D layout: col j = lane&15, row i = 4q + reg -> lag = 16i + j. acc = 1024*acf.
    float n00 = __int_as_float(__builtin_amdgcn_readfirstlane(__float_as_int(acc0[0])));
    float n01 = __int_as_float(__builtin_amdgcn_readfirstlane(__float_as_int(acc1[0])));
    float n0r0 = fmaxf(n00, 0.f);
    float n0r1 = fmaxf(n01, 0.f);
    float inv0 = (n0r0 == 0.f) ? (1.0f / 1024.0f) : (rsqrtf(n0r0) * (1.0f / 32.0f));
    float inv1 = (n0r1 == 0.f) ? (1.0f / 1024.0f) : (rsqrtf(n0r1) * (1.0f / 32.0f));

    const int G = blockIdx.x * 4 + fj;
    float* ob = out + (size_t)G * 256 + q * 64 + il;
    ob[ 0] = 0.5f * (fmaxf(acc0[0], 0.f) * inv0 + fmaxf(acc1[0], 0.f) * inv1);
    ob[16] = 0.5f * (fmaxf(acc0[1], 0.f) * inv0 + fmaxf(acc1[1], 0.f) * inv1);
    ob[32] = 0.5f * (fmaxf(acc0[2], 0.f) * inv0 + fmaxf(acc1[2], 0.f) * inv1);
    ob[48] = 0.5f * (fmaxf(acc0[3], 0.f) * inv0 + fmaxf(acc1[3], 0.f) * inv1);
}

extern "C" void kernel_launch(void* const* d_in, const int* in_sizes, int n_in,
                              void* d_out, int out_size, void* d_ws, size_t ws_size,
                              hipStream_t stream) {
    const float* in = (const float*)d_in[0];
    float* out = (float*)d_out;
    dim3 grid(15000);    // 60000 frames / 4 per block (1 wave per frame, both channels)
    dim3 block(256);
    acorr_fp8<<<grid, block, 0, stream>>>(in, out);
}